// Round 7
// baseline (2615.052 us; speedup 1.0000x reference)
//
#include <hip/hip_runtime.h>
#include <hip/hip_bf16.h>

typedef __attribute__((ext_vector_type(8))) short bf16x8;
typedef __attribute__((ext_vector_type(4))) float f32x4;
typedef __attribute__((ext_vector_type(4))) unsigned u32x4;

#define CDIM 1024
#define DDIM 1024
#define TDIM 1024
#define BK 32

__device__ __forceinline__ unsigned cvt_pk_bf16(float a, float b) {
    unsigned r;
    asm("v_cvt_pk_bf16_f32 %0, %1, %2" : "=v"(r) : "v"(a), "v"(b));
    return r;
}

// out[b,d,t] = sum_c x[b,c,t] * w[subj[b],c,d]
// 256(d) x 256(t) tile / block, 8 waves (512 thr), each wave 64(d)x128(t).
// bf16x3 split precision (hi*hi + hi*lo + lo*hi), fp32 MFMA accum.
// LDS row = d (or t), 8 granules x 8 shorts: g0-3 = hi(k0..31), g4-7 = lo.
// Slot swizzle swz(row) = (row ^ row>>3) & 7; lo-offset = hi-offset ^ 32
// shorts. Write rows step by 4, read rows by 1 -> both span 8 slots ->
// structural 2-way only (round-6 counter decode: 3.355e7 = 4/b128-read floor).
// T14: tile k+1 global->reg loads issued before converting tile k.

#define KSTEP(VCUR, VNXT, K0)                                                   \
  {                                                                             \
    const int ksafe = ((K0) + BK) & (CDIM - 1); /* last iter: dummy re-read */  \
    _Pragma("unroll")                                                           \
    for (int j = 0; j < 8; ++j)                                                 \
        VNXT[j] = *(const float4*)(sp + ((size_t)(ksafe + (cg << 3) + j) << 10)); \
    u32x4 hg[4], lg[4];                                                         \
    _Pragma("unroll")                                                           \
    for (int rr = 0; rr < 4; ++rr) {                                            \
      _Pragma("unroll")                                                         \
      for (int p = 0; p < 4; ++p) {                                             \
        const float f0 = VCUR[2 * p][rr];                                       \
        const float f1 = VCUR[2 * p + 1][rr];                                   \
        const unsigned h = cvt_pk_bf16(f0, f1);                                 \
        const float l0 = f0 - __uint_as_float(h << 16);                         \
        const float l1 = f1 - __uint_as_float(h & 0xFFFF0000u);                 \
        hg[rr][p] = h;                                                          \
        lg[rr][p] = cvt_pk_bf16(l0, l1);                                        \
      }                                                                         \
    }                                                                           \
    __syncthreads();                                                            \
    _Pragma("unroll")                                                           \
    for (int rr = 0; rr < 4; ++rr) {                                            \
      const int row = col0 + rr;                                                \
      short* sl = slds + row * 64;                                              \
      const int so = ((cg ^ ((row ^ (row >> 3)) & 7)) << 3);                    \
      *(u32x4*)(sl + so) = hg[rr];                                              \
      *(u32x4*)(sl + (so ^ 32)) = lg[rr];                                       \
    }                                                                           \
    __syncthreads();                                                            \
    bf16x8 ah[4], al[4];                                                        \
    _Pragma("unroll")                                                           \
    for (int m = 0; m < 4; ++m) {                                               \
      const short* wrow = Wt + (wdOff + m * 16 + fr) * 64;                      \
      ah[m] = *(const bf16x8*)(wrow + offHW[m]);                                \
      al[m] = *(const bf16x8*)(wrow + (offHW[m] ^ 32));                         \
    }                                                                           \
    _Pragma("unroll")                                                           \
    for (int n = 0; n < 8; ++n) {                                               \
      const short* xrow = Xt + (wtOff + n * 16 + fr) * 64;                      \
      const bf16x8 bh = *(const bf16x8*)(xrow + offHX[n]);                      \
      const bf16x8 bl = *(const bf16x8*)(xrow + (offHX[n] ^ 32));               \
      _Pragma("unroll")                                                         \
      for (int m = 0; m < 4; ++m) {                                             \
        acc[m][n] = __builtin_amdgcn_mfma_f32_16x16x32_bf16(ah[m], bh, acc[m][n], 0, 0, 0); \
        acc[m][n] = __builtin_amdgcn_mfma_f32_16x16x32_bf16(ah[m], bl, acc[m][n], 0, 0, 0); \
        acc[m][n] = __builtin_amdgcn_mfma_f32_16x16x32_bf16(al[m], bh, acc[m][n], 0, 0, 0); \
      }                                                                         \
    }                                                                           \
  }

__global__ __launch_bounds__(512, 4)
void subject_gemm(const float* __restrict__ x, const int* __restrict__ subj,
                  const float* __restrict__ w, float* __restrict__ out)
{
    __shared__ short Wt[256 * 64];   // 32 KB
    __shared__ short Xt[256 * 64];   // 32 KB  (total 64 KB -> 2 blocks/CU)

    // XCD mapping: 1024 blocks; bid&7 = XCD; 8 whole batches per XCD;
    // ttile fastest so consecutive slots share the W panel in L2.
    const int bid = blockIdx.x;
    const int xcd = bid & 7;
    const int slot = bid >> 3;               // 0..127 per XCD
    const int b = (xcd << 3) | (slot >> 4);  // 8 batches per XCD
    const int r = slot & 15;
    const int dtile = (r >> 2) << 8;
    const int ttile = (r & 3) << 8;

    const int s = subj[b];
    const float* __restrict__ wB = w + (size_t)s * (CDIM * DDIM);
    const float* __restrict__ xB = x + (size_t)b * (CDIM * TDIM);

    const int tid = threadIdx.x;
    const int lane = tid & 63;
    const int wave = tid >> 6;               // 0..7

    // ---- staging role: threads 0-255 stage W, 256-511 stage X ----
    const int ht = tid & 255;
    const int tq = ht & 63;            // column-quad 0..63 -> 256 cols
    const int cg = ht >> 6;            // k-granule 0..3 (8 c's each)
    const int col0 = tq << 2;
    const bool isW = (tid < 256);
    const float* sp = (isW ? wB + dtile : xB + ttile) + col0;
    short* slds = (isW ? Wt : Xt);

    // ---- fragment assignment: wave tile 64(d) x 128(t) ----
    const int wdOff = (wave >> 1) << 6;  // 0/64/128/192
    const int wtOff = (wave & 1) << 7;   // 0/128
    const int fr = lane & 15;
    const int fg = lane >> 4;

    int offHW[4], offHX[8];
    #pragma unroll
    for (int m = 0; m < 4; ++m) {
        const int rowW = wdOff + m * 16 + fr;
        offHW[m] = ((fg ^ ((rowW ^ (rowW >> 3)) & 7)) << 3);
    }
    #pragma unroll
    for (int n = 0; n < 8; ++n) {
        const int rowX = wtOff + n * 16 + fr;
        offHX[n] = ((fg ^ ((rowX ^ (rowX >> 3)) & 7)) << 3);
    }

    f32x4 acc[4][8] = {};

    // prologue: load tile 0
    float4 va[8], vb[8];
    #pragma unroll
    for (int j = 0; j < 8; ++j)
        va[j] = *(const float4*)(sp + ((size_t)((cg << 3) + j) << 10));

    for (int k0 = 0; k0 < CDIM; k0 += 2 * BK) {
        KSTEP(va, vb, k0);
        KSTEP(vb, va, k0 + BK);
    }

    // epilogue: C/D col = lane&15 (t), row = (lane>>4)*4 + q (d)
    float* __restrict__ oB = out + (size_t)b * (DDIM * TDIM)
                           + (size_t)(dtile + wdOff) * TDIM + (ttile + wtOff);
    #pragma unroll
    for (int m = 0; m < 4; ++m) {
        #pragma unroll
        for (int q = 0; q < 4; ++q) {
            const int d = m * 16 + (fg << 2) + q;
            float* orow = oB + (size_t)d * TDIM;
            #pragma unroll
            for (int n = 0; n < 8; ++n) {
                orow[n * 16 + fr] = acc[m][n][q];
            }
        }
    }
}

extern "C" void kernel_launch(void* const* d_in, const int* in_sizes, int n_in,
                              void* d_out, int out_size, void* d_ws, size_t ws_size,
                              hipStream_t stream) {
    const float* x = (const float*)d_in[0];
    const int* subjects = (const int*)d_in[1];
    const float* w = (const float*)d_in[2];
    float* out = (float*)d_out;
    subject_gemm<<<dim3(1024), dim3(512), 0, stream>>>(x, subjects, w, out);
}

// Round 8
// 384.338 us; speedup vs baseline: 6.8040x; 6.8040x over previous
//
#include <hip/hip_runtime.h>
#include <hip/hip_bf16.h>

typedef __attribute__((ext_vector_type(8))) short bf16x8;
typedef __attribute__((ext_vector_type(4))) float f32x4;
typedef __attribute__((ext_vector_type(4))) unsigned u32x4;

#define CDIM 1024
#define DDIM 1024
#define TDIM 1024
#define BK 32

__device__ __forceinline__ unsigned cvt_pk_bf16(float a, float b) {
    unsigned r;
    asm("v_cvt_pk_bf16_f32 %0, %1, %2" : "=v"(r) : "v"(a), "v"(b));
    return r;
}

// out[b,d,t] = sum_c x[b,c,t] * w[subj[b],c,d]
// 256(d) x 256(t) tile / block, 8 waves (512 thr), each wave 64(d)x128(t).
// bf16x3 split precision (hi*hi + hi*lo + lo*hi), fp32 MFMA accum.
// LDS row = d (or t), 8 granules x 8 shorts: g0-3 = hi(k0..31), g4-7 = lo.
// Slot swizzle swz(row) = (row ^ row>>3) & 7; lo-offset = hi ^ 32 shorts.
// T14: tile k+1 global->reg loads issued before converting tile k.
// __launch_bounds__(512,1): round-7 lesson — per-SIMD reg pool is 512, so
// (512,4) capped waves at 128 regs -> acc spilled to scratch (VGPR=64,
// 11 GB of spill traffic, 6% MfmaUtil). This kernel needs ~240 regs/wave
// -> 2 waves/SIMD, 1 block/CU (the HK 256^2 operating point).
#define KSTEP(VCUR, VNXT, K0)                                                   \
  {                                                                             \
    const int ksafe = ((K0) + BK) & (CDIM - 1); /* last iter: dummy re-read */  \
    _Pragma("unroll")                                                           \
    for (int j = 0; j < 8; ++j)                                                 \
        VNXT[j] = *(const float4*)(sp + ((size_t)(ksafe + (cg << 3) + j) << 10)); \
    u32x4 hg[4], lg[4];                                                         \
    _Pragma("unroll")                                                           \
    for (int rr = 0; rr < 4; ++rr) {                                            \
      _Pragma("unroll")                                                         \
      for (int p = 0; p < 4; ++p) {                                             \
        const float f0 = VCUR[2 * p][rr];                                       \
        const float f1 = VCUR[2 * p + 1][rr];                                   \
        const unsigned h = cvt_pk_bf16(f0, f1);                                 \
        const float l0 = f0 - __uint_as_float(h << 16);                         \
        const float l1 = f1 - __uint_as_float(h & 0xFFFF0000u);                 \
        hg[rr][p] = h;                                                          \
        lg[rr][p] = cvt_pk_bf16(l0, l1);                                        \
      }                                                                         \
    }                                                                           \
    __syncthreads();                                                            \
    _Pragma("unroll")                                                           \
    for (int rr = 0; rr < 4; ++rr) {                                            \
      const int row = col0 + rr;                                                \
      short* sl = slds + row * 64;                                              \
      const int so = ((cg ^ ((row ^ (row >> 3)) & 7)) << 3);                    \
      *(u32x4*)(sl + so) = hg[rr];                                              \
      *(u32x4*)(sl + (so ^ 32)) = lg[rr];                                       \
    }                                                                           \
    __syncthreads();                                                            \
    bf16x8 ah[4], al[4];                                                        \
    _Pragma("unroll")                                                           \
    for (int m = 0; m < 4; ++m) {                                               \
      const short* wrow = Wt + (wdOff + m * 16 + fr) * 64;                      \
      ah[m] = *(const bf16x8*)(wrow + offHW[m]);                                \
      al[m] = *(const bf16x8*)(wrow + (offHW[m] ^ 32));                         \
    }                                                                           \
    _Pragma("unroll")                                                           \
    for (int n = 0; n < 8; ++n) {                                               \
      const short* xrow = Xt + (wtOff + n * 16 + fr) * 64;                      \
      const bf16x8 bh = *(const bf16x8*)(xrow + offHX[n]);                      \
      const bf16x8 bl = *(const bf16x8*)(xrow + (offHX[n] ^ 32));               \
      _Pragma("unroll")                                                         \
      for (int m = 0; m < 4; ++m) {                                             \
        acc[m][n] = __builtin_amdgcn_mfma_f32_16x16x32_bf16(ah[m], bh, acc[m][n], 0, 0, 0); \
        acc[m][n] = __builtin_amdgcn_mfma_f32_16x16x32_bf16(ah[m], bl, acc[m][n], 0, 0, 0); \
        acc[m][n] = __builtin_amdgcn_mfma_f32_16x16x32_bf16(al[m], bh, acc[m][n], 0, 0, 0); \
      }                                                                         \
    }                                                                           \
  }

__global__ __launch_bounds__(512, 1)
void subject_gemm(const float* __restrict__ x, const int* __restrict__ subj,
                  const float* __restrict__ w, float* __restrict__ out)
{
    __shared__ short Wt[256 * 64];   // 32 KB
    __shared__ short Xt[256 * 64];   // 32 KB

    // XCD mapping: 1024 blocks; bid&7 = XCD; 8 whole batches per XCD;
    // ttile fastest so consecutive slots share the W panel in L2.
    const int bid = blockIdx.x;
    const int xcd = bid & 7;
    const int slot = bid >> 3;               // 0..127 per XCD
    const int b = (xcd << 3) | (slot >> 4);  // 8 batches per XCD
    const int r = slot & 15;
    const int dtile = (r >> 2) << 8;
    const int ttile = (r & 3) << 8;

    const int s = subj[b];
    const float* __restrict__ wB = w + (size_t)s * (CDIM * DDIM);
    const float* __restrict__ xB = x + (size_t)b * (CDIM * TDIM);

    const int tid = threadIdx.x;
    const int lane = tid & 63;
    const int wave = tid >> 6;               // 0..7

    // ---- staging role: threads 0-255 stage W, 256-511 stage X ----
    const int ht = tid & 255;
    const int tq = ht & 63;            // column-quad 0..63 -> 256 cols
    const int cg = ht >> 6;            // k-granule 0..3 (8 c's each)
    const int col0 = tq << 2;
    const bool isW = (tid < 256);
    const float* sp = (isW ? wB + dtile : xB + ttile) + col0;
    short* slds = (isW ? Wt : Xt);

    // ---- fragment assignment: wave tile 64(d) x 128(t) ----
    const int wdOff = (wave >> 1) << 6;  // 0/64/128/192
    const int wtOff = (wave & 1) << 7;   // 0/128
    const int fr = lane & 15;
    const int fg = lane >> 4;

    int offHW[4], offHX[8];
    #pragma unroll
    for (int m = 0; m < 4; ++m) {
        const int rowW = wdOff + m * 16 + fr;
        offHW[m] = ((fg ^ ((rowW ^ (rowW >> 3)) & 7)) << 3);
    }
    #pragma unroll
    for (int n = 0; n < 8; ++n) {
        const int rowX = wtOff + n * 16 + fr;
        offHX[n] = ((fg ^ ((rowX ^ (rowX >> 3)) & 7)) << 3);
    }

    f32x4 acc[4][8] = {};

    // prologue: load tile 0
    float4 va[8], vb[8];
    #pragma unroll
    for (int j = 0; j < 8; ++j)
        va[j] = *(const float4*)(sp + ((size_t)((cg << 3) + j) << 10));

    for (int k0 = 0; k0 < CDIM; k0 += 2 * BK) {
        KSTEP(va, vb, k0);
        KSTEP(vb, va, k0 + BK);
    }

    // epilogue: C/D col = lane&15 (t), row = (lane>>4)*4 + q (d)
    float* __restrict__ oB = out + (size_t)b * (DDIM * TDIM)
                           + (size_t)(dtile + wdOff) * TDIM + (ttile + wtOff);
    #pragma unroll
    for (int m = 0; m < 4; ++m) {
        #pragma unroll
        for (int q = 0; q < 4; ++q) {
            const int d = m * 16 + (fg << 2) + q;
            float* orow = oB + (size_t)d * TDIM;
            #pragma unroll
            for (int n = 0; n < 8; ++n) {
                orow[n * 16 + fr] = acc[m][n][q];
            }
        }
    }
}

extern "C" void kernel_launch(void* const* d_in, const int* in_sizes, int n_in,
                              void* d_out, int out_size, void* d_ws, size_t ws_size,
                              hipStream_t stream) {
    const float* x = (const float*)d_in[0];
    const int* subjects = (const int*)d_in[1];
    const float* w = (const float*)d_in[2];
    float* out = (float*)d_out;
    subject_gemm<<<dim3(1024), dim3(512), 0, stream>>>(x, subjects, w, out);
}

// Round 9
// 377.481 us; speedup vs baseline: 6.9276x; 1.0182x over previous
//
#include <hip/hip_runtime.h>
#include <hip/hip_bf16.h>

typedef __attribute__((ext_vector_type(8))) short bf16x8;
typedef __attribute__((ext_vector_type(4))) float f32x4;
typedef __attribute__((ext_vector_type(4))) unsigned u32x4;

#define CDIM 1024
#define DDIM 1024
#define TDIM 1024
#define BK 32

__device__ __forceinline__ unsigned cvt_pk_bf16(float a, float b) {
    unsigned r;
    asm("v_cvt_pk_bf16_f32 %0, %1, %2" : "=v"(r) : "v"(a), "v"(b));
    return r;
}

// out[b,d,t] = sum_c x[b,c,t] * w[subj[b],c,d]
// 256(d) x 256(t) tile / block, 8 waves (512 thr), each wave 64(d)x128(t).
// bf16x3 split precision (hi*hi + hi*lo + lo*hi), fp32 MFMA accum.
// LDS row = d (or t), 8 granules x 8 shorts: g0-3 = hi(k0..31), g4-7 = lo.
// Slot swizzle swz(row) = (row ^ row>>3) & 7; lo-offset = hi ^ 32 shorts.
// T14: tile k+1 global->reg loads issued before converting tile k.
// __launch_bounds__(512,1): 8-wave block => 2 waves/SIMD => <=256 unified
// regs/wave (round-7: (512,4) forced a spill catastrophe).
// Round-8 lesson: the 3 same-acc MFMAs (hh/hl/lh) were issued back-to-back
// -> C-dependency latency (~20-30cy) per MFMA, 7875 cy/step vs 3725 floor.
// Fix: pair-of-n schedule -> 8 independent MFMAs between same-acc reuses.

#define KSTEP(VCUR, VNXT, K0)                                                   \
  {                                                                             \
    const int ksafe = ((K0) + BK) & (CDIM - 1); /* last iter: dummy re-read */  \
    _Pragma("unroll")                                                           \
    for (int j = 0; j < 8; ++j)                                                 \
        VNXT[j] = *(const float4*)(sp + ((size_t)(ksafe + (cg << 3) + j) << 10)); \
    u32x4 hg[4], lg[4];                                                         \
    _Pragma("unroll")                                                           \
    for (int rr = 0; rr < 4; ++rr) {                                            \
      _Pragma("unroll")                                                         \
      for (int p = 0; p < 4; ++p) {                                             \
        const float f0 = VCUR[2 * p][rr];                                       \
        const float f1 = VCUR[2 * p + 1][rr];                                   \
        const unsigned h = cvt_pk_bf16(f0, f1);                                 \
        const float l0 = f0 - __uint_as_float(h << 16);                         \
        const float l1 = f1 - __uint_as_float(h & 0xFFFF0000u);                 \
        hg[rr][p] = h;                                                          \
        lg[rr][p] = cvt_pk_bf16(l0, l1);                                        \
      }                                                                         \
    }                                                                           \
    __syncthreads();                                                            \
    _Pragma("unroll")                                                           \
    for (int rr = 0; rr < 4; ++rr) {                                            \
      const int row = col0 + rr;                                                \
      short* sl = slds + row * 64;                                              \
      const int so = ((cg ^ ((row ^ (row >> 3)) & 7)) << 3);                    \
      *(u32x4*)(sl + so) = hg[rr];                                              \
      *(u32x4*)(sl + (so ^ 32)) = lg[rr];                                       \
    }                                                                           \
    __syncthreads();                                                            \
    bf16x8 ah[4], al[4];                                                        \
    _Pragma("unroll")                                                           \
    for (int m = 0; m < 4; ++m) {                                               \
      const short* wrow = Wt + (wdOff + m * 16 + fr) * 64;                      \
      ah[m] = *(const bf16x8*)(wrow + offHW[m]);                                \
      al[m] = *(const bf16x8*)(wrow + (offHW[m] ^ 32));                         \
    }                                                                           \
    _Pragma("unroll")                                                           \
    for (int np = 0; np < 4; ++np) {                                            \
      const int n0 = 2 * np, n1 = 2 * np + 1;                                   \
      const short* xr0 = Xt + (wtOff + n0 * 16 + fr) * 64;                      \
      const short* xr1 = Xt + (wtOff + n1 * 16 + fr) * 64;                      \
      const bf16x8 bh0 = *(const bf16x8*)(xr0 + offHX[n0]);                     \
      const bf16x8 bl0 = *(const bf16x8*)(xr0 + (offHX[n0] ^ 32));              \
      const bf16x8 bh1 = *(const bf16x8*)(xr1 + offHX[n1]);                     \
      const bf16x8 bl1 = *(const bf16x8*)(xr1 + (offHX[n1] ^ 32));              \
      _Pragma("unroll")                                                         \
      for (int m = 0; m < 4; ++m)                                               \
        acc[m][n0] = __builtin_amdgcn_mfma_f32_16x16x32_bf16(ah[m], bh0, acc[m][n0], 0, 0, 0); \
      _Pragma("unroll")                                                         \
      for (int m = 0; m < 4; ++m)                                               \
        acc[m][n1] = __builtin_amdgcn_mfma_f32_16x16x32_bf16(ah[m], bh1, acc[m][n1], 0, 0, 0); \
      _Pragma("unroll")                                                         \
      for (int m = 0; m < 4; ++m)                                               \
        acc[m][n0] = __builtin_amdgcn_mfma_f32_16x16x32_bf16(ah[m], bl0, acc[m][n0], 0, 0, 0); \
      _Pragma("unroll")                                                         \
      for (int m = 0; m < 4; ++m)                                               \
        acc[m][n1] = __builtin_amdgcn_mfma_f32_16x16x32_bf16(ah[m], bl1, acc[m][n1], 0, 0, 0); \
      _Pragma("unroll")                                                         \
      for (int m = 0; m < 4; ++m)                                               \
        acc[m][n0] = __builtin_amdgcn_mfma_f32_16x16x32_bf16(al[m], bh0, acc[m][n0], 0, 0, 0); \
      _Pragma("unroll")                                                         \
      for (int m = 0; m < 4; ++m)                                               \
        acc[m][n1] = __builtin_amdgcn_mfma_f32_16x16x32_bf16(al[m], bh1, acc[m][n1], 0, 0, 0); \
    }                                                                           \
  }

__global__ __launch_bounds__(512, 1)
void subject_gemm(const float* __restrict__ x, const int* __restrict__ subj,
                  const float* __restrict__ w, float* __restrict__ out)
{
    __shared__ short Wt[256 * 64];   // 32 KB
    __shared__ short Xt[256 * 64];   // 32 KB

    // XCD mapping: 1024 blocks; bid&7 = XCD; 8 whole batches per XCD;
    // ttile fastest so consecutive slots share the W panel in L2.
    const int bid = blockIdx.x;
    const int xcd = bid & 7;
    const int slot = bid >> 3;               // 0..127 per XCD
    const int b = (xcd << 3) | (slot >> 4);  // 8 batches per XCD
    const int r = slot & 15;
    const int dtile = (r >> 2) << 8;
    const int ttile = (r & 3) << 8;

    const int s = subj[b];
    const float* __restrict__ wB = w + (size_t)s * (CDIM * DDIM);
    const float* __restrict__ xB = x + (size_t)b * (CDIM * TDIM);

    const int tid = threadIdx.x;
    const int lane = tid & 63;
    const int wave = tid >> 6;               // 0..7

    // ---- staging role: threads 0-255 stage W, 256-511 stage X ----
    const int ht = tid & 255;
    const int tq = ht & 63;            // column-quad 0..63 -> 256 cols
    const int cg = ht >> 6;            // k-granule 0..3 (8 c's each)
    const int col0 = tq << 2;
    const bool isW = (tid < 256);
    const float* sp = (isW ? wB + dtile : xB + ttile) + col0;
    short* slds = (isW ? Wt : Xt);

    // ---- fragment assignment: wave tile 64(d) x 128(t) ----
    const int wdOff = (wave >> 1) << 6;  // 0/64/128/192
    const int wtOff = (wave & 1) << 7;   // 0/128
    const int fr = lane & 15;
    const int fg = lane >> 4;

    int offHW[4], offHX[8];
    #pragma unroll
    for (int m = 0; m < 4; ++m) {
        const int rowW = wdOff + m * 16 + fr;
        offHW[m] = ((fg ^ ((rowW ^ (rowW >> 3)) & 7)) << 3);
    }
    #pragma unroll
    for (int n = 0; n < 8; ++n) {
        const int rowX = wtOff + n * 16 + fr;
        offHX[n] = ((fg ^ ((rowX ^ (rowX >> 3)) & 7)) << 3);
    }

    f32x4 acc[4][8] = {};

    // prologue: load tile 0
    float4 va[8], vb[8];
    #pragma unroll
    for (int j = 0; j < 8; ++j)
        va[j] = *(const float4*)(sp + ((size_t)((cg << 3) + j) << 10));

    for (int k0 = 0; k0 < CDIM; k0 += 2 * BK) {
        KSTEP(va, vb, k0);
        KSTEP(vb, va, k0 + BK);
    }

    // epilogue: C/D col = lane&15 (t), row = (lane>>4)*4 + q (d)
    float* __restrict__ oB = out + (size_t)b * (DDIM * TDIM)
                           + (size_t)(dtile + wdOff) * TDIM + (ttile + wtOff);
    #pragma unroll
    for (int m = 0; m < 4; ++m) {
        #pragma unroll
        for (int q = 0; q < 4; ++q) {
            const int d = m * 16 + (fg << 2) + q;
            float* orow = oB + (size_t)d * TDIM;
            #pragma unroll
            for (int n = 0; n < 8; ++n) {
                orow[n * 16 + fr] = acc[m][n][q];
            }
        }
    }
}

extern "C" void kernel_launch(void* const* d_in, const int* in_sizes, int n_in,
                              void* d_out, int out_size, void* d_ws, size_t ws_size,
                              hipStream_t stream) {
    const float* x = (const float*)d_in[0];
    const int* subjects = (const int*)d_in[1];
    const float* w = (const float*)d_in[2];
    float* out = (float*)d_out;
    subject_gemm<<<dim3(1024), dim3(512), 0, stream>>>(x, subjects, w, out);
}